// Round 3
// baseline (1457.925 us; speedup 1.0000x reference)
//
#include <hip/hip_runtime.h>
#include <hip/hip_bf16.h>

#define LEAK 0.2f

// ---------------------------------------------------------------------------
// LDS-tiled direct conv + leaky ReLU, v2.
// - Even/odd column-split LDS layout when ST==2 (bank-conflict-free reads)
// - kh-outer compute loop: only K fragment regs live -> no LDS re-reads
// - __launch_bounds__(256,4): allow up to ~128 VGPRs
// Block = (batch b, channel-group cog of CPT, output tile TH x TW).
// ---------------------------------------------------------------------------
template<int CI, int CO, int K, int ST, int P, int IH, int IW, int OH, int OW,
         int TH, int TW, int CC, int CPT>
__global__ __launch_bounds__(256, 4) void conv_tile_k(const float* __restrict__ x,
                                                      const float* __restrict__ w,
                                                      const float* __restrict__ bias,
                                                      float* __restrict__ y) {
    constexpr int KK  = K * K;
    constexpr int ITH = (TH - 1) * ST + K;
    constexpr int ITW = (TW - 1) * ST + K;
    constexpr int HALF = (ST == 2) ? (ITW + 1) / 2 : 0;      // even-col count
    constexpr int SPr  = (ST == 2) ? (HALF + ITW / 2) : ITW;
    constexpr int SP   = (SPr & 1) ? SPr : SPr + 1;          // odd row stride
    constexpr int NTW  = OW / TW;
    constexpr int COG  = CO / CPT;

    __shared__ float tile[CC * ITH * SP];

    const int tid = threadIdx.x;
    const int bx  = blockIdx.x;
    const int tr  = bx / NTW, tc = bx % NTW;
    const int bg  = blockIdx.y;
    const int cog = bg % COG;
    const int b   = bg / COG;

    const int ih_base = tr * TH * ST - P;
    const int iw_base = tc * TW * ST - P;

    const int wid = tid >> 6, lane = tid & 63;
    const int ty = tid / TW, tx = tid % TW;
    const bool active = tid < TH * TW;

    float acc[CPT];
#pragma unroll
    for (int j = 0; j < CPT; ++j) acc[j] = bias[cog * CPT + j];

    const float* __restrict__ xb = x + (size_t)b * CI * IH * IW;
    const float* __restrict__ wb = w + (size_t)cog * CPT * CI * KK;

    for (int ci0 = 0; ci0 < CI; ci0 += CC) {
        __syncthreads();
        // ---- stage CC channels, zero-filled halo, split-parity layout ----
        {
            int row = wid, cc = 0;
            for (int p = wid; p < CC * ITH; p += 4) {
                int ih = ih_base + row;
                bool rowok = (unsigned)ih < (unsigned)IH;
                const float* __restrict__ src =
                    xb + ((size_t)(ci0 + cc) * IH + ih) * IW;
                float* __restrict__ dst = tile + (cc * ITH + row) * SP;
                {
                    int c = lane;
                    if (c < ITW) {
                        int iw = iw_base + c;
                        float v = (rowok && (unsigned)iw < (unsigned)IW) ? src[iw] : 0.0f;
                        dst[(ST == 2) ? ((c & 1) * HALF + (c >> 1)) : c] = v;
                    }
                }
                if (ITW > 64) {
                    int c = lane + 64;
                    if (c < ITW) {
                        int iw = iw_base + c;
                        float v = (rowok && (unsigned)iw < (unsigned)IW) ? src[iw] : 0.0f;
                        dst[(ST == 2) ? ((c & 1) * HALF + (c >> 1)) : c] = v;
                    }
                }
                row += 4;
                if (row >= ITH) { row -= ITH; ++cc; }
            }
        }
        __syncthreads();

        // ---- compute: kh-outer, K fragment regs live ----
        if (active) {
            for (int cc = 0; cc < CC; ++cc) {
                const float* __restrict__ wp = wb + (size_t)(ci0 + cc) * KK;
                const float* __restrict__ tb = tile + (cc * ITH + ty * ST) * SP;
#pragma unroll
                for (int kh = 0; kh < K; ++kh) {
                    float xv[K];
#pragma unroll
                    for (int kw = 0; kw < K; ++kw)
                        xv[kw] = tb[kh * SP +
                                    ((ST == 2) ? ((kw & 1) * HALF + tx + (kw >> 1))
                                               : (tx + kw))];
#pragma unroll
                    for (int j = 0; j < CPT; ++j) {
#pragma unroll
                        for (int kw = 0; kw < K; ++kw)
                            acc[j] += xv[kw] * wp[(size_t)j * CI * KK + kh * K + kw];
                    }
                }
            }
        }
    }

    if (active) {
        int oh = tr * TH + ty, ow = tc * TW + tx;
        float* __restrict__ yo =
            y + (((size_t)b * CO + cog * CPT) * OH + oh) * OW + ow;
#pragma unroll
        for (int j = 0; j < CPT; ++j) {
            float a = acc[j];
            yo[(size_t)j * OH * OW] = a > 0.0f ? a : LEAK * a;
        }
    }
}

// ---------------------------------------------------------------------------
// ROI bilinear sampling. One block per (b, r). Output layout S[b][c][r][p]
// byte-identical to the reference reshape quirk.
// ---------------------------------------------------------------------------
__global__ __launch_bounds__(256) void roi_k(const float* __restrict__ feat,
                                             const float* __restrict__ roi,
                                             float* __restrict__ S) {
    int b = blockIdx.x >> 5;
    int r = blockIdx.x & 31;
    const float* rr = roi + (size_t)(b * 32 + r) * 7;

    __shared__ int   offA[100], offB[100], offC[100], offD[100];
    __shared__ float wA[100], wB[100], wC[100], wD[100];

    int tid = threadIdx.x;
    if (tid < 100) {
        int i = tid / 10, j = tid % 10;
        float cx = rr[0], cy = rr[1];
        float W1 = rr[2], W2 = rr[3], H1 = rr[4], H2 = rr[5], psi = rr[6];
        float offx = ((float)j - 4.5f) / 10.0f;
        float offy = ((float)i - 4.5f) / 10.0f;
        float gx = offx * (W1 + W2) - (W1 - W2) * 0.5f;
        float gy = offy * (H1 + H2) - (H1 - H2) * 0.5f;
        float sn = sinf(psi), cs = cosf(psi);
        float xs = gx * cs + gy * sn + cx;
        float ys = -gx * sn + gy * cs + cy;

        float x0f = floorf(xs), y0f = floorf(ys);
        int x0 = (int)x0f, x1 = x0 + 1;
        int y0 = (int)y0f, y1 = y0 + 1;
        x0 = min(max(x0, 0), 55); x1 = min(max(x1, 0), 55);
        y0 = min(max(y0, 0), 55); y1 = min(max(y1, 0), 55);
        float fx0 = (float)x0, fx1 = (float)x1;
        float fy0 = (float)y0, fy1 = (float)y1;
        float step = (fx1 - fx0) * (fy1 - fy0);
        step = fminf(fmaxf(step, 0.001f), 2.0f);
        float inv = 1.0f / step;
        wA[tid] = (fx1 - xs) * (fy1 - ys) * inv;
        wB[tid] = (fx1 - xs) * (ys - fy0) * inv;
        wC[tid] = (xs - fx0) * (fy1 - ys) * inv;
        wD[tid] = (xs - fx0) * (ys - fy0) * inv;
        offA[tid] = y0 * 56 + x0;
        offB[tid] = y1 * 56 + x0;
        offC[tid] = y0 * 56 + x1;
        offD[tid] = y1 * 56 + x1;
    }
    __syncthreads();

    const float* __restrict__ fb = feat + (size_t)b * 128 * 3136;
    float* __restrict__ outb = S + ((size_t)b * 128 * 32 + r) * 100;
    int c = tid / 100;            // one division at entry
    int p = tid - c * 100;
    for (int t = tid; t < 12800; t += 256) {
        const float* f = fb + c * 3136;
        float v = wA[p] * f[offA[p]] + wB[p] * f[offB[p]] +
                  wC[p] * f[offC[p]] + wD[p] * f[offD[p]];
        outb[(size_t)c * 3200 + p] = v;
        p += 56; c += 2;                     // 256 = 2*100 + 56
        if (p >= 100) { p -= 100; ++c; }
    }
}

// ---------------------------------------------------------------------------
// FC split-K GEMM: part[ks][m][n]; M=1024 N=256 K=12800, 8 K-splits of 1600.
// 64x64 tile, BK=16, 4x4 micro. Grid (4, 16, 8) = 512 blocks x 256 threads.
// ---------------------------------------------------------------------------
__global__ __launch_bounds__(256) void fc_gemm_k(const float* __restrict__ A,
                                                 const float* __restrict__ Wt,
                                                 float* __restrict__ part) {
    constexpr int BK = 16;
    constexpr int KSLICE = 1600;
    __shared__ float As[BK][64];
    __shared__ float Ws[BK][64];

    int tid = threadIdx.x;
    int bn = blockIdx.x, bm = blockIdx.y, ks = blockIdx.z;
    int tx = tid & 15, ty = tid >> 4;
    int lm = tid >> 2;
    int lk = (tid & 3) * 4;

    float c[4][4] = {};

    const float* __restrict__ Ab = A  + (size_t)(bm * 64 + lm) * 12800 + ks * KSLICE + lk;
    const float* __restrict__ Wb = Wt + (size_t)(bn * 64 + lm) * 12800 + ks * KSLICE + lk;

    for (int k0 = 0; k0 < KSLICE; k0 += BK) {
        float4 a4 = *(const float4*)(Ab + k0);
        float4 w4 = *(const float4*)(Wb + k0);
        __syncthreads();
        As[lk + 0][lm] = a4.x; As[lk + 1][lm] = a4.y;
        As[lk + 2][lm] = a4.z; As[lk + 3][lm] = a4.w;
        Ws[lk + 0][lm] = w4.x; Ws[lk + 1][lm] = w4.y;
        Ws[lk + 2][lm] = w4.z; Ws[lk + 3][lm] = w4.w;
        __syncthreads();
#pragma unroll
        for (int k = 0; k < BK; ++k) {
            float4 av = *(const float4*)&As[k][ty * 4];
            float4 wv = *(const float4*)&Ws[k][tx * 4];
            c[0][0] += av.x * wv.x; c[0][1] += av.x * wv.y;
            c[0][2] += av.x * wv.z; c[0][3] += av.x * wv.w;
            c[1][0] += av.y * wv.x; c[1][1] += av.y * wv.y;
            c[1][2] += av.y * wv.z; c[1][3] += av.y * wv.w;
            c[2][0] += av.z * wv.x; c[2][1] += av.z * wv.y;
            c[2][2] += av.z * wv.z; c[2][3] += av.z * wv.w;
            c[3][0] += av.w * wv.x; c[3][1] += av.w * wv.y;
            c[3][2] += av.w * wv.z; c[3][3] += av.w * wv.w;
        }
    }

    float* __restrict__ po = part + ((size_t)ks * 1024 + bm * 64 + ty * 4) * 256
                                  + bn * 64 + tx * 4;
#pragma unroll
    for (int i = 0; i < 4; ++i) {
        float4 v = make_float4(c[i][0], c[i][1], c[i][2], c[i][3]);
        *(float4*)(po + (size_t)i * 256) = v;
    }
}

__global__ __launch_bounds__(256) void fc_reduce_k(const float* __restrict__ part,
                                                   const float* __restrict__ bias,
                                                   float* __restrict__ out) {
    int i = blockIdx.x * 256 + threadIdx.x;
    float s = bias[i & 255];
#pragma unroll
    for (int ks = 0; ks < 8; ++ks) s += part[(size_t)ks * 262144 + i];
    out[i] = s;
}

// ---------------------------------------------------------------------------
extern "C" void kernel_launch(void* const* d_in, const int* in_sizes, int n_in,
                              void* d_out, int out_size, void* d_ws, size_t ws_size,
                              hipStream_t stream) {
    const float* x   = (const float*)d_in[0];
    const float* ROI = (const float*)d_in[1];
    const float* w1  = (const float*)d_in[2];
    const float* b1  = (const float*)d_in[3];
    const float* w2  = (const float*)d_in[4];
    const float* b2  = (const float*)d_in[5];
    const float* w3  = (const float*)d_in[6];
    const float* b3  = (const float*)d_in[7];
    const float* fcw = (const float*)d_in[8];
    const float* fcb = (const float*)d_in[9];
    float* out = (float*)d_out;

    char* ws = (char*)d_ws;
    // c1: [0, 51,380,224)           32*32*112*112*4
    // c2: [51,380,224, 77,070,336)  32*64*56*56*4
    // c3: [77,070,336, 128,450,560) 32*128*56*56*4
    // S : [0, 52,428,800)           (c1 + head of c2 dead by ROI time)
    // part: [52,428,800, 61,817,408) 8*1024*256*4 (c2 dead by FC time)
    float* c1   = (float*)(ws);
    float* c2   = (float*)(ws + 51380224);
    float* c3   = (float*)(ws + 77070336);
    float* S    = (float*)(ws);
    float* part = (float*)(ws + 52428800);

    // conv1: (32,3,224,224) -> (32,32,112,112), K=5,S=2,P=2
    conv_tile_k<3, 32, 5, 2, 2, 224, 224, 112, 112, 4, 56, 3, 16>
        <<<dim3(28 * 2, 32 * 2), 256, 0, stream>>>(x, w1, b1, c1);
    // conv2: -> (32,64,56,56), K=5,S=2,P=2
    conv_tile_k<32, 64, 5, 2, 2, 112, 112, 56, 56, 4, 56, 4, 16>
        <<<dim3(14, 32 * 4), 256, 0, stream>>>(c1, w2, b2, c2);
    // conv3: -> (32,128,56,56), K=3,S=1,P=1, CPT=32 (32 FMA per LDS read)
    conv_tile_k<64, 128, 3, 1, 1, 56, 56, 56, 56, 4, 56, 16, 32>
        <<<dim3(14, 32 * 4), 256, 0, stream>>>(c2, w3, b3, c3);
    // ROI sampling -> S[b][c][r][p]
    roi_k<<<1024, 256, 0, stream>>>(c3, ROI, S);
    // FC split-K + reduce
    fc_gemm_k<<<dim3(4, 16, 8), 256, 0, stream>>>(S, fcw, part);
    fc_reduce_k<<<1024, 256, 0, stream>>>(part, fcb, out);
}

// Round 4
// 1035.930 us; speedup vs baseline: 1.4074x; 1.4074x over previous
//
#include <hip/hip_runtime.h>
#include <hip/hip_bf16.h>

#define LEAK 0.2f

// ---------------------------------------------------------------------------
// Padded-input conv + leaky ReLU. All inputs pre-padded in HBM -> staging is
// a pure linear float4 copy (no bounds logic). Full-width tiles (TW == 56).
// Each thread: 1 output pixel x CPT output channels; weights wave-uniform.
// ---------------------------------------------------------------------------
template<int CI, int CO, int K, int ST, int PIH, int PIW,
         int OH, int OW, int TH, int TW, int CC, int CPT,
         int OPW, int OP>
__global__ __launch_bounds__(256, 4) void conv_pad_k(
    const float* __restrict__ in, const float* __restrict__ w,
    const float* __restrict__ bias, float* __restrict__ out)
{
    constexpr int KK  = K * K;
    constexpr int ITH = (TH - 1) * ST + K;
    constexpr int ITW = (TW - 1) * ST + K;
    constexpr int SW  = ((ITW + 3) / 4) * 4;     // staged cols (float4 rounded)
    constexpr int SW4 = SW / 4;
    constexpr int NF4 = CC * ITH * SW4;          // float4s per staging round
    constexpr int NTW = OW / TW;
    constexpr int COG = CO / CPT;
    constexpr int OSH = OH + 2 * OP;

    __shared__ float tile[CC * ITH * SW];

    const int tid = threadIdx.x;
    const int tr  = blockIdx.x / NTW;
    const int tc  = blockIdx.x % NTW;
    const int cog = blockIdx.y % COG;
    const int b   = blockIdx.y / COG;

    const int ty = tid / TW, tx = tid % TW;
    const bool active = tid < TH * TW;

    float acc[CPT];
#pragma unroll
    for (int j = 0; j < CPT; ++j) acc[j] = bias[cog * CPT + j];

    const float* __restrict__ wb = w + (size_t)cog * CPT * CI * KK;

    for (int ci0 = 0; ci0 < CI; ci0 += CC) {
        const float* __restrict__ gb =
            in + ((size_t)(b * CI + ci0) * PIH + tr * TH * ST) * PIW + tc * TW * ST;
        __syncthreads();
        // ---- staging: straight float4 copy, no masks except tail ----
#pragma unroll
        for (int it = 0; it < (NF4 + 255) / 256; ++it) {
            int t = tid + it * 256;
            if ((NF4 % 256 == 0) || t < NF4) {
                int cc  = t / (ITH * SW4);
                int r2  = t - cc * (ITH * SW4);
                int row = r2 / SW4;
                int c4  = r2 - row * SW4;
                float4 v = *(const float4*)(gb + (size_t)cc * PIH * PIW + row * PIW + c4 * 4);
                *(float4*)&tile[t * 4] = v;
            }
        }
        __syncthreads();

        // ---- compute: kh-outer, K fragment regs live ----
        if (active) {
            for (int cc = 0; cc < CC; ++cc) {
                const float* __restrict__ wp = wb + (size_t)(ci0 + cc) * KK;
                const float* __restrict__ tb = tile + (cc * ITH + ty * ST) * SW + tx * ST;
#pragma unroll
                for (int kh = 0; kh < K; ++kh) {
                    float xv[K];
#pragma unroll
                    for (int kw = 0; kw < K; ++kw) xv[kw] = tb[kh * SW + kw];
#pragma unroll
                    for (int j = 0; j < CPT; ++j) {
#pragma unroll
                        for (int kw = 0; kw < K; ++kw)
                            acc[j] += xv[kw] * wp[(size_t)j * CI * KK + kh * K + kw];
                    }
                }
            }
        }
    }

    if (active) {
        int oh = tr * TH + ty + OP, ow = tc * TW + tx + OP;
        float* __restrict__ yo =
            out + (((size_t)b * CO + cog * CPT) * OSH + oh) * OPW + ow;
#pragma unroll
        for (int j = 0; j < CPT; ++j) {
            float a = acc[j];
            yo[(size_t)j * OSH * OPW] = a > 0.0f ? a : LEAK * a;
        }
    }
}

// ---------------------------------------------------------------------------
// x -> x_pad [32*3][228][228], 2-pixel zero border. Block = 4 rows of one ch.
// ---------------------------------------------------------------------------
__global__ __launch_bounds__(256) void pad_x_k(const float* __restrict__ x,
                                               float* __restrict__ xp) {
    int blk = blockIdx.x;              // 32*3*57
    int r4 = blk % 57, ic = blk / 57;
    int wid = threadIdx.x >> 6, lane = threadIdx.x & 63;
    int row = r4 * 4 + wid;
    const float* __restrict__ src = x + (size_t)ic * 224 * 224 + (size_t)(row - 2) * 224;
    float* __restrict__ dst = xp + (size_t)ic * 228 * 228 + (size_t)row * 228;
    bool rok = (row >= 2) && (row < 226);
    for (int c = lane; c < 228; c += 64) {
        float v = 0.0f;
        if (rok && c >= 2 && c < 226) v = src[c - 2];
        dst[c] = v;
    }
}

// Zero the 2-wide border of one 116x116 channel plane. grid = 1024.
__global__ __launch_bounds__(256) void zb_c1p_k(float* __restrict__ p) {
    float* base = p + (size_t)blockIdx.x * 13456;
    for (int t = threadIdx.x; t < 912; t += 256) {
        int idx;
        if (t < 464) {                     // rows 0,1,114,115 full width
            int r = t / 116, c = t - r * 116;
            int row = (r < 2) ? r : r + 112;
            idx = row * 116 + c;
        } else {                           // rows 2..113, cols 0,1,114,115
            int s = t - 464;
            int r = s >> 2, c = s & 3;
            int col = (c < 2) ? c : c + 112;
            idx = (r + 2) * 116 + col;
        }
        base[idx] = 0.0f;
    }
}

// Zero the 1-wide border of one 58x60 channel plane (row 0, row 57, cols 0/57).
// grid = 2048, block 64.
__global__ __launch_bounds__(64) void zb_c2p_k(float* __restrict__ p) {
    float* base = p + (size_t)blockIdx.x * 3480;
    for (int t = threadIdx.x; t < 232; t += 64) {
        int idx;
        if (t < 120) {                     // rows 0 and 57, cols 0..59
            int r = t / 60, c = t - r * 60;
            idx = (r == 0 ? 0 : 57) * 60 + c;
        } else {
            int s = t - 120;
            int r = (s >> 1) + 1;
            idx = r * 60 + ((s & 1) ? 57 : 0);
        }
        base[idx] = 0.0f;
    }
}

// ---------------------------------------------------------------------------
// ROI bilinear sampling (unchanged). Output layout S[b][c][r][p] matches the
// reference reshape quirk byte-for-byte.
// ---------------------------------------------------------------------------
__global__ __launch_bounds__(256) void roi_k(const float* __restrict__ feat,
                                             const float* __restrict__ roi,
                                             float* __restrict__ S) {
    int b = blockIdx.x >> 5;
    int r = blockIdx.x & 31;
    const float* rr = roi + (size_t)(b * 32 + r) * 7;

    __shared__ int   offA[100], offB[100], offC[100], offD[100];
    __shared__ float wA[100], wB[100], wC[100], wD[100];

    int tid = threadIdx.x;
    if (tid < 100) {
        int i = tid / 10, j = tid % 10;
        float cx = rr[0], cy = rr[1];
        float W1 = rr[2], W2 = rr[3], H1 = rr[4], H2 = rr[5], psi = rr[6];
        float offx = ((float)j - 4.5f) / 10.0f;
        float offy = ((float)i - 4.5f) / 10.0f;
        float gx = offx * (W1 + W2) - (W1 - W2) * 0.5f;
        float gy = offy * (H1 + H2) - (H1 - H2) * 0.5f;
        float sn = sinf(psi), cs = cosf(psi);
        float xs = gx * cs + gy * sn + cx;
        float ys = -gx * sn + gy * cs + cy;

        float x0f = floorf(xs), y0f = floorf(ys);
        int x0 = (int)x0f, x1 = x0 + 1;
        int y0 = (int)y0f, y1 = y0 + 1;
        x0 = min(max(x0, 0), 55); x1 = min(max(x1, 0), 55);
        y0 = min(max(y0, 0), 55); y1 = min(max(y1, 0), 55);
        float fx0 = (float)x0, fx1 = (float)x1;
        float fy0 = (float)y0, fy1 = (float)y1;
        float step = (fx1 - fx0) * (fy1 - fy0);
        step = fminf(fmaxf(step, 0.001f), 2.0f);
        float inv = 1.0f / step;
        wA[tid] = (fx1 - xs) * (fy1 - ys) * inv;
        wB[tid] = (fx1 - xs) * (ys - fy0) * inv;
        wC[tid] = (xs - fx0) * (fy1 - ys) * inv;
        wD[tid] = (xs - fx0) * (ys - fy0) * inv;
        offA[tid] = y0 * 56 + x0;
        offB[tid] = y1 * 56 + x0;
        offC[tid] = y0 * 56 + x1;
        offD[tid] = y1 * 56 + x1;
    }
    __syncthreads();

    const float* __restrict__ fb = feat + (size_t)b * 128 * 3136;
    float* __restrict__ outb = S + ((size_t)b * 128 * 32 + r) * 100;
    int c = tid / 100;
    int p = tid - c * 100;
    for (int t = tid; t < 12800; t += 256) {
        const float* f = fb + c * 3136;
        float v = wA[p] * f[offA[p]] + wB[p] * f[offB[p]] +
                  wC[p] * f[offC[p]] + wD[p] * f[offD[p]];
        outb[(size_t)c * 3200 + p] = v;
        p += 56; c += 2;
        if (p >= 100) { p -= 100; ++c; }
    }
}

// ---------------------------------------------------------------------------
// FC split-K GEMM (unchanged): M=1024 N=256 K=12800, 8 K-splits of 1600.
// ---------------------------------------------------------------------------
__global__ __launch_bounds__(256) void fc_gemm_k(const float* __restrict__ A,
                                                 const float* __restrict__ Wt,
                                                 float* __restrict__ part) {
    constexpr int BK = 16;
    constexpr int KSLICE = 1600;
    __shared__ float As[BK][64];
    __shared__ float Ws[BK][64];

    int tid = threadIdx.x;
    int bn = blockIdx.x, bm = blockIdx.y, ks = blockIdx.z;
    int tx = tid & 15, ty = tid >> 4;
    int lm = tid >> 2;
    int lk = (tid & 3) * 4;

    float c[4][4] = {};

    const float* __restrict__ Ab = A  + (size_t)(bm * 64 + lm) * 12800 + ks * KSLICE + lk;
    const float* __restrict__ Wb = Wt + (size_t)(bn * 64 + lm) * 12800 + ks * KSLICE + lk;

    for (int k0 = 0; k0 < KSLICE; k0 += BK) {
        float4 a4 = *(const float4*)(Ab + k0);
        float4 w4 = *(const float4*)(Wb + k0);
        __syncthreads();
        As[lk + 0][lm] = a4.x; As[lk + 1][lm] = a4.y;
        As[lk + 2][lm] = a4.z; As[lk + 3][lm] = a4.w;
        Ws[lk + 0][lm] = w4.x; Ws[lk + 1][lm] = w4.y;
        Ws[lk + 2][lm] = w4.z; Ws[lk + 3][lm] = w4.w;
        __syncthreads();
#pragma unroll
        for (int k = 0; k < BK; ++k) {
            float4 av = *(const float4*)&As[k][ty * 4];
            float4 wv = *(const float4*)&Ws[k][tx * 4];
            c[0][0] += av.x * wv.x; c[0][1] += av.x * wv.y;
            c[0][2] += av.x * wv.z; c[0][3] += av.x * wv.w;
            c[1][0] += av.y * wv.x; c[1][1] += av.y * wv.y;
            c[1][2] += av.y * wv.z; c[1][3] += av.y * wv.w;
            c[2][0] += av.z * wv.x; c[2][1] += av.z * wv.y;
            c[2][2] += av.z * wv.z; c[2][3] += av.z * wv.w;
            c[3][0] += av.w * wv.x; c[3][1] += av.w * wv.y;
            c[3][2] += av.w * wv.z; c[3][3] += av.w * wv.w;
        }
    }

    float* __restrict__ po = part + ((size_t)ks * 1024 + bm * 64 + ty * 4) * 256
                                  + bn * 64 + tx * 4;
#pragma unroll
    for (int i = 0; i < 4; ++i) {
        float4 v = make_float4(c[i][0], c[i][1], c[i][2], c[i][3]);
        *(float4*)(po + (size_t)i * 256) = v;
    }
}

__global__ __launch_bounds__(256) void fc_reduce_k(const float* __restrict__ part,
                                                   const float* __restrict__ bias,
                                                   float* __restrict__ out) {
    int i = blockIdx.x * 256 + threadIdx.x;
    float s = bias[i & 255];
#pragma unroll
    for (int ks = 0; ks < 8; ++ks) s += part[(size_t)ks * 262144 + i];
    out[i] = s;
}

// ---------------------------------------------------------------------------
extern "C" void kernel_launch(void* const* d_in, const int* in_sizes, int n_in,
                              void* d_out, int out_size, void* d_ws, size_t ws_size,
                              hipStream_t stream) {
    const float* x   = (const float*)d_in[0];
    const float* ROI = (const float*)d_in[1];
    const float* w1  = (const float*)d_in[2];
    const float* b1  = (const float*)d_in[3];
    const float* w2  = (const float*)d_in[4];
    const float* b2  = (const float*)d_in[5];
    const float* w3  = (const float*)d_in[6];
    const float* b3  = (const float*)d_in[7];
    const float* fcw = (const float*)d_in[8];
    const float* fcb = (const float*)d_in[9];
    float* out = (float*)d_out;

    char* ws = (char*)d_ws;
    // Workspace map (peak ~116 MB, < 128.45 MB proven safe in rounds 1-3):
    //  c1p  [0,           55,115,776)   32*32*116*116*4   (alive conv1..conv2)
    //  c2p  [55,115,776,  83,623,936)   32*64*58*60*4     (alive conv2..conv3)
    //  xpad [83,623,936, 103,575,040)   32*3*228*228*4    (alive pad..conv1)
    //  c3   [0,           51,380,224)   32*128*56*56*4    (alive conv3..roi; c1p dead)
    //  S    [55,115,776, 107,544,576)   32*128*32*100*4   (alive roi..fc; c2p/xpad dead)
    //  part [107,544,576,115,933,184)   8*1024*256*4      (alive fc..reduce)
    float* c1p  = (float*)(ws);
    float* c2p  = (float*)(ws + 55115776);
    float* xpad = (float*)(ws + 83623936);
    float* c3   = (float*)(ws);
    float* S    = (float*)(ws + 55115776);
    float* part = (float*)(ws + 107544576);

    // Pad/zero prep (workspace is re-poisoned to 0xAA before every call).
    pad_x_k<<<32 * 3 * 57, 256, 0, stream>>>(x, xpad);
    zb_c1p_k<<<1024, 256, 0, stream>>>(c1p);
    zb_c2p_k<<<2048, 64, 0, stream>>>(c2p);

    // conv1: xpad (32,3,228,228) -> c1p interior (112x112), K=5,S=2
    conv_pad_k<3, 32, 5, 2, 228, 228, 112, 112, 4, 56, 3, 16, 116, 2>
        <<<dim3(28 * 2, 32 * 2), 256, 0, stream>>>(xpad, w1, b1, c1p);
    // conv2: c1p (116x116) -> c2p interior (56x56), K=5,S=2
    conv_pad_k<32, 64, 5, 2, 116, 116, 56, 56, 4, 56, 4, 16, 60, 1>
        <<<dim3(14, 32 * 4), 256, 0, stream>>>(c1p, w2, b2, c2p);
    // conv3: c2p (58x60) -> c3 (56x56), K=3,S=1
    conv_pad_k<64, 128, 3, 1, 58, 60, 56, 56, 4, 56, 16, 16, 56, 0>
        <<<dim3(14, 32 * 8), 256, 0, stream>>>(c2p, w3, b3, c3);

    // ROI sampling -> S[b][c][r][p]
    roi_k<<<1024, 256, 0, stream>>>(c3, ROI, S);
    // FC split-K + reduce
    fc_gemm_k<<<dim3(4, 16, 8), 256, 0, stream>>>(S, fcw, part);
    fc_reduce_k<<<1024, 256, 0, stream>>>(part, fcb, out);
}

// Round 5
// 769.699 us; speedup vs baseline: 1.8941x; 1.3459x over previous
//
#include <hip/hip_runtime.h>
#include <hip/hip_bf16.h>

#define LEAK 0.2f

__device__ __forceinline__ float lrelu(float a) { return a > 0.0f ? a : LEAK * a; }

// ---------------------------------------------------------------------------
// Implicit-GEMM conv + leaky ReLU.  out[co][pix] = sum_k wT[k][co]*B[k][pix]
// B[k][pix] gathered from pre-padded input; wT pre-transposed [k][co].
// Block: CO x NT output tile (NT pixels = consecutive n within one image,
// all dims divide exactly).  256 threads, micro-tile MR co x 4 px.
// Double-buffered LDS, ONE barrier per K-step:
//   gather(0); loop { write(p); sync; gather(it+1); compute(p); }
// ---------------------------------------------------------------------------
template<int CI, int ST, int KH, int KW, int KIN, int KP,
         int PIH, int PIW, int LP, int OW, int PPI,
         int CO, int NT, int MR, int OSH, int OSW, int OR0, int OC0>
__global__ __launch_bounds__(256, 4) void conv_gemm_k(
    const float* __restrict__ in,    // padded input [img*CI + ci][PIH][PIW]
    const float* __restrict__ wT,    // [KP][CO]
    const float* __restrict__ bias,
    float* __restrict__ out)
{
    constexpr int KT  = KP / 16;        // K-step count
    constexpr int TXW = NT / 4;         // pixel quads per tile
    constexpr int BT  = 16 * NT / 4;    // B staging quad-tasks
    constexpr int AT  = 16 * CO / 4;    // A staging float4 tasks
    constexpr int BI  = (BT + 255) / 256;
    constexpr int AI  = (AT + 255) / 256;
    constexpr int ASZ = 16 * CO;
    constexpr int BSZ = 16 * NT;

    __shared__ float sm[2 * ASZ + 2 * BSZ];

    const int tid = threadIdx.x;
    const int bx  = blockIdx.x;
    const int tx  = tid % TXW;
    const int ty  = tid / TXW;

    // ---- per-thread staging geometry (K-independent) ----
    int bofs[BI], bkl[BI], bpq[BI];
#pragma unroll
    for (int q = 0; q < BI; ++q) {
        int task = tid + q * 256;
        if ((BT % 256 == 0) || task < BT) {
            int kl  = task / TXW;
            int pxq = task % TXW;
            int px0 = bx * NT + pxq * 4;
            int img = px0 / PPI;
            int n   = px0 % PPI;
            int oh  = n / OW, ow = n % OW;
            bofs[q] = ((img * CI) * PIH + oh * ST) * PIW + ow * ST + LP;
            bkl[q]  = kl;
            bpq[q]  = pxq;
        }
    }
    int aofs[AI];
#pragma unroll
    for (int p = 0; p < AI; ++p) {
        int task = tid + p * 256;
        if ((AT % 256 == 0) || task < AT)
            aofs[p] = (task / (CO / 4)) * CO + (task % (CO / 4)) * 4;
    }

    float  br[BI][4];
    float4 ar[AI];

    // gather K-step `it` into registers
    auto gather = [&](int it) {
        int k0 = it * 16;
#pragma unroll
        for (int q = 0; q < BI; ++q) {
            int task = tid + q * 256;
            if ((BT % 256 == 0) || task < BT) {
                int k = k0 + bkl[q];
                if (KP > KIN) k = min(k, KIN - 1);   // padded-K tail (weights are 0)
                int ci  = k / (KH * KW);
                int rem = k - ci * (KH * KW);
                int kh  = rem / KW;
                int kw  = rem - kh * KW;
                const float* __restrict__ s = in + bofs[q] + (ci * PIH + kh) * PIW + kw;
                br[q][0] = s[0]; br[q][1] = s[ST]; br[q][2] = s[2 * ST]; br[q][3] = s[3 * ST];
            }
        }
#pragma unroll
        for (int p = 0; p < AI; ++p) {
            int task = tid + p * 256;
            if ((AT % 256 == 0) || task < AT)
                ar[p] = *(const float4*)&wT[(size_t)k0 * CO + aofs[p]];
        }
    };

    float acc[MR][4];
#pragma unroll
    for (int j = 0; j < MR; ++j) {
        float bv = bias[ty * MR + j];
#pragma unroll
        for (int i = 0; i < 4; ++i) acc[j][i] = bv;
    }

    gather(0);
    for (int it = 0; it < KT; ++it) {
        const int p = it & 1;
        float* __restrict__ Asb = sm + p * ASZ;
        float* __restrict__ Bsb = sm + 2 * ASZ + p * BSZ;
        // write staged regs -> LDS buffer p
#pragma unroll
        for (int pa = 0; pa < AI; ++pa) {
            int task = tid + pa * 256;
            if ((AT % 256 == 0) || task < AT)
                *(float4*)&Asb[aofs[pa]] = ar[pa];
        }
#pragma unroll
        for (int q = 0; q < BI; ++q) {
            int task = tid + q * 256;
            if ((BT % 256 == 0) || task < BT)
                *(float4*)&Bsb[bkl[q] * NT + bpq[q] * 4] =
                    make_float4(br[q][0], br[q][1], br[q][2], br[q][3]);
        }
        __syncthreads();
        if (it + 1 < KT) gather(it + 1);
        // compute from buffer p
#pragma unroll
        for (int k = 0; k < 16; ++k) {
            float4 b4 = *(const float4*)&Bsb[k * NT + tx * 4];
#pragma unroll
            for (int j4 = 0; j4 < MR; j4 += 4) {
                float4 a4 = *(const float4*)&Asb[k * CO + ty * MR + j4];
                acc[j4 + 0][0] += a4.x * b4.x; acc[j4 + 0][1] += a4.x * b4.y;
                acc[j4 + 0][2] += a4.x * b4.z; acc[j4 + 0][3] += a4.x * b4.w;
                acc[j4 + 1][0] += a4.y * b4.x; acc[j4 + 1][1] += a4.y * b4.y;
                acc[j4 + 1][2] += a4.y * b4.z; acc[j4 + 1][3] += a4.y * b4.w;
                acc[j4 + 2][0] += a4.z * b4.x; acc[j4 + 2][1] += a4.z * b4.y;
                acc[j4 + 2][2] += a4.z * b4.z; acc[j4 + 2][3] += a4.z * b4.w;
                acc[j4 + 3][0] += a4.w * b4.x; acc[j4 + 3][1] += a4.w * b4.y;
                acc[j4 + 3][2] += a4.w * b4.z; acc[j4 + 3][3] += a4.w * b4.w;
            }
        }
    }

    // ---- store (aligned float4: OC0 and ow are 4-aligned) ----
    {
        int pxs = bx * NT + tx * 4;
        int img = pxs / PPI;
        int n   = pxs % PPI;
        int oh  = n / OW, ow = n % OW;
#pragma unroll
        for (int j = 0; j < MR; ++j) {
            int co = ty * MR + j;
            float4 v = make_float4(lrelu(acc[j][0]), lrelu(acc[j][1]),
                                   lrelu(acc[j][2]), lrelu(acc[j][3]));
            size_t off = (((size_t)img * CO + co) * OSH + (oh + OR0)) * OSW + (ow + OC0);
            *(float4*)&out[off] = v;
        }
    }
}

// ---------------------------------------------------------------------------
// Weight transpose: wT[k][co] = w[co][k], K padded to KP with zeros.
// ---------------------------------------------------------------------------
template<int CO, int KIN, int KP>
__global__ __launch_bounds__(256) void wtr_k(const float* __restrict__ w,
                                             float* __restrict__ wT) {
    int i = blockIdx.x * 256 + threadIdx.x;
    if (i >= KP * CO) return;
    int k = i / CO, co = i % CO;
    wT[i] = (k < KIN) ? w[(size_t)co * KIN + k] : 0.0f;
}

// ---------------------------------------------------------------------------
// x -> x_pad [32*3][228][228], 2-pixel zero border.
// ---------------------------------------------------------------------------
__global__ __launch_bounds__(256) void pad_x_k(const float* __restrict__ x,
                                               float* __restrict__ xp) {
    int blk = blockIdx.x;              // 32*3*57
    int r4 = blk % 57, ic = blk / 57;
    int wid = threadIdx.x >> 6, lane = threadIdx.x & 63;
    int row = r4 * 4 + wid;
    const float* __restrict__ src = x + (size_t)ic * 224 * 224 + (size_t)(row - 2) * 224;
    float* __restrict__ dst = xp + (size_t)ic * 228 * 228 + (size_t)row * 228;
    bool rok = (row >= 2) && (row < 226);
    for (int c = lane; c < 228; c += 64) {
        float v = 0.0f;
        if (rok && c >= 2 && c < 226) v = src[c - 2];
        dst[c] = v;
    }
}

// c1p plane = 116 x 120; logical col c -> layout col c+2 (data ow at col ow+4).
// Zero rows 0,1,114,115 (full width) + layout cols {2,3,116,117} rows 2..113.
__global__ __launch_bounds__(256) void zb_c1p_k(float* __restrict__ p) {
    float* base = p + (size_t)blockIdx.x * (116 * 120);
    for (int t = threadIdx.x; t < 928; t += 256) {
        int idx;
        if (t < 480) {
            int r = t / 120, c = t - r * 120;
            int row = (r < 2) ? r : r + 112;
            idx = row * 120 + c;
        } else {
            int s = t - 480;
            int r = s >> 2, c = s & 3;
            int col = (c < 2) ? (c + 2) : (c + 114);   // 2,3,116,117
            idx = (r + 2) * 120 + col;
        }
        base[idx] = 0.0f;
    }
}

// c2p plane = 58 x 64; logical col g -> layout col g+3 (data ow at col ow+4).
// Zero rows 0,57 (full width) + layout cols {3,60} rows 1..56.
__global__ __launch_bounds__(64) void zb_c2p_k(float* __restrict__ p) {
    float* base = p + (size_t)blockIdx.x * (58 * 64);
    for (int t = threadIdx.x; t < 240; t += 64) {
        int idx;
        if (t < 128) {
            int r = t >> 6, c = t & 63;
            idx = (r ? 57 : 0) * 64 + c;
        } else {
            int s = t - 128;
            int r = (s >> 1) + 1;
            idx = r * 64 + ((s & 1) ? 60 : 3);
        }
        base[idx] = 0.0f;
    }
}

// ---------------------------------------------------------------------------
// ROI bilinear sampling (unchanged). Output layout S[b][c][r][p] matches the
// reference reshape quirk byte-for-byte.
// ---------------------------------------------------------------------------
__global__ __launch_bounds__(256) void roi_k(const float* __restrict__ feat,
                                             const float* __restrict__ roi,
                                             float* __restrict__ S) {
    int b = blockIdx.x >> 5;
    int r = blockIdx.x & 31;
    const float* rr = roi + (size_t)(b * 32 + r) * 7;

    __shared__ int   offA[100], offB[100], offC[100], offD[100];
    __shared__ float wA[100], wB[100], wC[100], wD[100];

    int tid = threadIdx.x;
    if (tid < 100) {
        int i = tid / 10, j = tid % 10;
        float cx = rr[0], cy = rr[1];
        float W1 = rr[2], W2 = rr[3], H1 = rr[4], H2 = rr[5], psi = rr[6];
        float offx = ((float)j - 4.5f) / 10.0f;
        float offy = ((float)i - 4.5f) / 10.0f;
        float gx = offx * (W1 + W2) - (W1 - W2) * 0.5f;
        float gy = offy * (H1 + H2) - (H1 - H2) * 0.5f;
        float sn = sinf(psi), cs = cosf(psi);
        float xs = gx * cs + gy * sn + cx;
        float ys = -gx * sn + gy * cs + cy;

        float x0f = floorf(xs), y0f = floorf(ys);
        int x0 = (int)x0f, x1 = x0 + 1;
        int y0 = (int)y0f, y1 = y0 + 1;
        x0 = min(max(x0, 0), 55); x1 = min(max(x1, 0), 55);
        y0 = min(max(y0, 0), 55); y1 = min(max(y1, 0), 55);
        float fx0 = (float)x0, fx1 = (float)x1;
        float fy0 = (float)y0, fy1 = (float)y1;
        float step = (fx1 - fx0) * (fy1 - fy0);
        step = fminf(fmaxf(step, 0.001f), 2.0f);
        float inv = 1.0f / step;
        wA[tid] = (fx1 - xs) * (fy1 - ys) * inv;
        wB[tid] = (fx1 - xs) * (ys - fy0) * inv;
        wC[tid] = (xs - fx0) * (fy1 - ys) * inv;
        wD[tid] = (xs - fx0) * (ys - fy0) * inv;
        offA[tid] = y0 * 56 + x0;
        offB[tid] = y1 * 56 + x0;
        offC[tid] = y0 * 56 + x1;
        offD[tid] = y1 * 56 + x1;
    }
    __syncthreads();

    const float* __restrict__ fb = feat + (size_t)b * 128 * 3136;
    float* __restrict__ outb = S + ((size_t)b * 128 * 32 + r) * 100;
    int c = tid / 100;
    int p = tid - c * 100;
    for (int t = tid; t < 12800; t += 256) {
        const float* f = fb + c * 3136;
        float v = wA[p] * f[offA[p]] + wB[p] * f[offB[p]] +
                  wC[p] * f[offC[p]] + wD[p] * f[offD[p]];
        outb[(size_t)c * 3200 + p] = v;
        p += 56; c += 2;
        if (p >= 100) { p -= 100; ++c; }
    }
}

// ---------------------------------------------------------------------------
// FC split-K GEMM (unchanged): M=1024 N=256 K=12800, 8 K-splits of 1600.
// ---------------------------------------------------------------------------
__global__ __launch_bounds__(256) void fc_gemm_k(const float* __restrict__ A,
                                                 const float* __restrict__ Wt,
                                                 float* __restrict__ part) {
    constexpr int BK = 16;
    constexpr int KSLICE = 1600;
    __shared__ float As[BK][64];
    __shared__ float Ws[BK][64];

    int tid = threadIdx.x;
    int bn = blockIdx.x, bm = blockIdx.y, ks = blockIdx.z;
    int tx = tid & 15, ty = tid >> 4;
    int lm = tid >> 2;
    int lk = (tid & 3) * 4;

    float c[4][4] = {};

    const float* __restrict__ Ab = A  + (size_t)(bm * 64 + lm) * 12800 + ks * KSLICE + lk;
    const float* __restrict__ Wb = Wt + (size_t)(bn * 64 + lm) * 12800 + ks * KSLICE + lk;

    for (int k0 = 0; k0 < KSLICE; k0 += BK) {
        float4 a4 = *(const float4*)(Ab + k0);
        float4 w4 = *(const float4*)(Wb + k0);
        __syncthreads();
        As[lk + 0][lm] = a4.x; As[lk + 1][lm] = a4.y;
        As[lk + 2][lm] = a4.z; As[lk + 3][lm] = a4.w;
        Ws[lk + 0][lm] = w4.x; Ws[lk + 1][lm] = w4.y;
        Ws[lk + 2][lm] = w4.z; Ws[lk + 3][lm] = w4.w;
        __syncthreads();
#pragma unroll
        for (int k = 0; k < BK; ++k) {
            float4 av = *(const float4*)&As[k][ty * 4];
            float4 wv = *(const float4*)&Ws[k][tx * 4];
            c[0][0] += av.x * wv.x; c[0][1] += av.x * wv.y;
            c[0][2] += av.x * wv.z; c[0][3] += av.x * wv.w;
            c[1][0] += av.y * wv.x; c[1][1] += av.y * wv.y;
            c[1][2] += av.y * wv.z; c[1][3] += av.y * wv.w;
            c[2][0] += av.z * wv.x; c[2][1] += av.z * wv.y;
            c[2][2] += av.z * wv.z; c[2][3] += av.z * wv.w;
            c[3][0] += av.w * wv.x; c[3][1] += av.w * wv.y;
            c[3][2] += av.w * wv.z; c[3][3] += av.w * wv.w;
        }
    }

    float* __restrict__ po = part + ((size_t)ks * 1024 + bm * 64 + ty * 4) * 256
                                  + bn * 64 + tx * 4;
#pragma unroll
    for (int i = 0; i < 4; ++i) {
        float4 v = make_float4(c[i][0], c[i][1], c[i][2], c[i][3]);
        *(float4*)(po + (size_t)i * 256) = v;
    }
}

__global__ __launch_bounds__(256) void fc_reduce_k(const float* __restrict__ part,
                                                   const float* __restrict__ bias,
                                                   float* __restrict__ out) {
    int i = blockIdx.x * 256 + threadIdx.x;
    float s = bias[i & 255];
#pragma unroll
    for (int ks = 0; ks < 8; ++ks) s += part[(size_t)ks * 262144 + i];
    out[i] = s;
}

// ---------------------------------------------------------------------------
extern "C" void kernel_launch(void* const* d_in, const int* in_sizes, int n_in,
                              void* d_out, int out_size, void* d_ws, size_t ws_size,
                              hipStream_t stream) {
    const float* x   = (const float*)d_in[0];
    const float* ROI = (const float*)d_in[1];
    const float* w1  = (const float*)d_in[2];
    const float* b1  = (const float*)d_in[3];
    const float* w2  = (const float*)d_in[4];
    const float* b2  = (const float*)d_in[5];
    const float* w3  = (const float*)d_in[6];
    const float* b3  = (const float*)d_in[7];
    const float* fcw = (const float*)d_in[8];
    const float* fcb = (const float*)d_in[9];
    float* out = (float*)d_out;

    char* ws = (char*)d_ws;
    // Workspace (peak ~117.8 MB < 128.45 MB used in earlier rounds):
    //  c1p  [0,           57,016,320)  32*32*116*120*4   conv1 -> conv2
    //  c2p  [57,016,320,  87,425,024)  32*64*58*64*4     conv2 -> conv3
    //  xpad [87,425,024, 107,386,880)  32*3*228*228*4    pad  -> conv1
    //  wT1  [107,386,880,107,397,120)  80*32*4
    //  wT2  [107,397,120,107,601,920)  800*64*4
    //  wT3  [107,601,920,107,896,832)  576*128*4
    //  c3   [0,           51,380,224)  32*128*56*56*4    conv3 -> roi (c1p dead)
    //  S    [57,016,320, 109,445,120)  roi -> fc (c2p/xpad/wT dead)
    //  part [109,445,120,117,833,728)  fc -> reduce
    float* c1p  = (float*)(ws);
    float* c2p  = (float*)(ws + 57016320);
    float* xpad = (float*)(ws + 87425024);
    float* wT1  = (float*)(ws + 107386880);
    float* wT2  = (float*)(ws + 107397120);
    float* wT3  = (float*)(ws + 107601920);
    float* c3   = (float*)(ws);
    float* S    = (float*)(ws + 57016320);
    float* part = (float*)(ws + 109445120);

    // prep: weight transposes, input pad, border zeroing
    wtr_k<32,  75, 80 ><<<10,  256, 0, stream>>>(w1, wT1);
    wtr_k<64,  800, 800><<<200, 256, 0, stream>>>(w2, wT2);
    wtr_k<128, 576, 576><<<288, 256, 0, stream>>>(w3, wT3);
    pad_x_k<<<32 * 3 * 57, 256, 0, stream>>>(x, xpad);
    zb_c1p_k<<<1024, 256, 0, stream>>>(c1p);
    zb_c2p_k<<<2048, 64, 0, stream>>>(c2p);

    // conv1: xpad(228x228,LP=0) -> c1p(116x120, OR0=2, OC0=4). 32co x 128px.
    conv_gemm_k<3, 2, 5, 5, 75, 80, 228, 228, 0, 112, 12544,
                32, 128, 4, 116, 120, 2, 4>
        <<<3136, 256, 0, stream>>>(xpad, wT1, b1, c1p);
    // conv2: c1p(116x120,LP=2) -> c2p(58x64, OR0=1, OC0=4). 64co x 64px.
    conv_gemm_k<32, 2, 5, 5, 800, 800, 116, 120, 2, 56, 3136,
                64, 64, 4, 58, 64, 1, 4>
        <<<1568, 256, 0, stream>>>(c1p, wT2, b2, c2p);
    // conv3: c2p(58x64,LP=3) -> c3 flat(56x56). 128co x 64px, 8x4 micro.
    conv_gemm_k<64, 1, 3, 3, 576, 576, 58, 64, 3, 56, 3136,
                128, 64, 8, 56, 56, 0, 0>
        <<<1568, 256, 0, stream>>>(c2p, wT3, b3, c3);

    // ROI sampling -> S[b][c][r][p]
    roi_k<<<1024, 256, 0, stream>>>(c3, ROI, S);
    // FC split-K + reduce
    fc_gemm_k<<<dim3(4, 16, 8), 256, 0, stream>>>(S, fcw, part);
    fc_reduce_k<<<1024, 256, 0, stream>>>(part, fcb, out);
}